// Round 8
// baseline (681.106 us; speedup 1.0000x reference)
//
#include <hip/hip_runtime.h>
#include <math.h>

#define TT 2048

typedef __attribute__((ext_vector_type(8))) short bfrag;   // 8 bf16 in 4 VGPRs
typedef __attribute__((ext_vector_type(4))) float facc;    // 4 fp32 acc

#define NEG_BIG (-1.0e30f)

typedef __attribute__((address_space(1))) const void gas_void;
typedef __attribute__((address_space(3))) void las_void;

__device__ __forceinline__ void gl_lds16(const void* g, void* l) {
    __builtin_amdgcn_global_load_lds((gas_void*)g, (las_void*)l, 16, 0, 0);
}

__device__ __forceinline__ unsigned short f2b(float f) {
    union { float f; unsigned int i; } v; v.f = f;
    unsigned int b = v.i;
    return (unsigned short)((b + 0x7FFFu + ((b >> 16) & 1u)) >> 16);  // RNE
}
__device__ __forceinline__ float b2f(unsigned short s) {
    union { unsigned int i; float f; } u; u.i = ((unsigned int)s) << 16; return u.f;
}
__device__ __forceinline__ void cvt8_f32(const float* __restrict__ p, unsigned short* d) {
    float4 lo = *(const float4*)p, hi = *(const float4*)(p + 4);
    d[0] = f2b(lo.x); d[1] = f2b(lo.y); d[2] = f2b(lo.z); d[3] = f2b(lo.w);
    d[4] = f2b(hi.x); d[5] = f2b(hi.y); d[6] = f2b(hi.z); d[7] = f2b(hi.w);
}

// ---------------------------------------------------------------------------
// fp32 -> bf16 flat convert (n8 = count of 8-element chunks)
// ---------------------------------------------------------------------------
__global__ __launch_bounds__(256) void k_cvt(const float* __restrict__ in,
                                             unsigned short* __restrict__ out, int n8) {
    int c = blockIdx.x * 256 + threadIdx.x;
    if (c < n8) {
        unsigned short t[8];
        cvt8_f32(in + (size_t)c * 8, t);
        *(uint4*)(out + (size_t)c * 8) = *(const uint4*)t;
    }
}

// ---------------------------------------------------------------------------
// Weight transpose+convert: W (2048 x N fp32, row-major) -> WT (N x 2048 bf16)
// ---------------------------------------------------------------------------
__global__ __launch_bounds__(256) void k_wt(const float* __restrict__ W,
                                            unsigned short* __restrict__ WT, int N) {
    __shared__ alignas(16) unsigned short tile[64][72];
    int r0 = blockIdx.y * 64, c0 = blockIdx.x * 64;
    int tid = threadIdx.x;
    for (int i = 0; i < 2; ++i) {
        int c = tid + i * 256;
        int row = c >> 3, c8 = (c & 7) * 8;
        unsigned short t[8];
        cvt8_f32(W + (size_t)(r0 + row) * N + c0 + c8, t);
        *(uint4*)&tile[row][c8] = *(const uint4*)t;
    }
    __syncthreads();
    for (int i = 0; i < 2; ++i) {
        int c = tid + i * 256;
        int col = c >> 3, r8 = (c & 7) * 8;
        unsigned short t[8];
        for (int j = 0; j < 8; ++j) t[j] = tile[r8 + j][col];
        *(uint4*)(WT + (size_t)(c0 + col) * 2048 + r0 + r8) = *(const uint4*)t;
    }
}

// ---------------------------------------------------------------------------
// V transpose: QKV (8192 x 3072 bf16, V = cols 2560..3071) -> VbT (512 x 8192)
// ---------------------------------------------------------------------------
__global__ __launch_bounds__(256) void k_vt(const unsigned short* __restrict__ QKV,
                                            unsigned short* __restrict__ VbT) {
    __shared__ alignas(16) unsigned short tile[64][72];
    int r0 = blockIdx.y * 64, c0 = blockIdx.x * 64;
    int tid = threadIdx.x;
    for (int i = 0; i < 2; ++i) {
        int c = tid + i * 256;
        int row = c >> 3, c8 = (c & 7) * 8;
        *(uint4*)&tile[row][c8] =
            *(const uint4*)(QKV + (size_t)(r0 + row) * 3072 + 2560 + c0 + c8);
    }
    __syncthreads();
    for (int i = 0; i < 2; ++i) {
        int c = tid + i * 256;
        int col = c >> 3, r8 = (c & 7) * 8;
        unsigned short t[8];
        for (int j = 0; j < 8; ++j) t[j] = tile[r8 + j][col];
        *(uint4*)(VbT + (size_t)(c0 + col) * 8192 + r0 + r8) = *(const uint4*)t;
    }
}

// ---------------------------------------------------------------------------
// 2-phase double-buffered m97 GEMM (round-6/7 winner). SWZ selects the LDS
// chunk swizzle for the within-run A/B:
//   SWZ=0: full 3-bit XOR  chunk ^= row&7   (round-7 control; 4.7e7 conflicts)
//   SWZ=1: st_16x32-style  chunk ^= (row&4)>>1  (m201's measured-good swizzle,
//          141x conflict reduction on identical [row][128B] geometry)
// Writer keeps linear LDS dest (gl_lds16 rule #21); the inverse permutation
// is applied to the per-lane GLOBAL source chunk; reader applies it on the
// ds_read slot. Self-inverse XOR both sides.
// ---------------------------------------------------------------------------
template <int SWZ>
__global__ __launch_bounds__(256) void k_gemm2ph(const unsigned short* __restrict__ A,
                                                 const unsigned short* __restrict__ Bt,
                                                 void* __restrict__ Cmat,
                                                 int M, int N, int K, int outF) {
    __shared__ union SM {
        struct { unsigned short A[2][128][64]; unsigned short B[2][128][64]; } s;  // 64 KB
        unsigned short ct[32][136];
        float          ctf[32][136];
    } sm;
    int tid = threadIdx.x;
    int w = tid >> 6, lane = tid & 63, quad = lane >> 4, l15 = lane & 15;
    int m0 = blockIdx.y * 128, n0 = blockIdx.x * 128;
    int wm = (w >> 1) * 64, wn = (w & 1) * 64;

    int srow   = lane >> 3;                 // 0..7
    // source chunk = (lane&7) ^ swz(row), row&7 == lane>>3 within each issue
    int schunk = SWZ ? ((lane & 7) ^ ((lane & 32) >> 4))
                     : ((lane & 7) ^ (lane >> 3));
    // reader swizzle term (frag rows have row&7 == l15&7)
    int rsw = SWZ ? ((l15 & 4) >> 1) : (l15 & 7);

    facc acc[4][4];
#pragma unroll
    for (int mi = 0; mi < 4; ++mi)
#pragma unroll
        for (int ni = 0; ni < 4; ++ni)
#pragma unroll
            for (int r = 0; r < 4; ++r) acc[mi][ni][r] = 0.f;

    auto stage = [&](int bb, int k0) {
#pragma unroll
        for (int i = 0; i < 4; ++i) {
            int row = w * 32 + i * 8;
            gl_lds16(A  + (size_t)(m0 + row + srow) * K + k0 + schunk * 8, &sm.s.A[bb][row][0]);
            gl_lds16(Bt + (size_t)(n0 + row + srow) * K + k0 + schunk * 8, &sm.s.B[bb][row][0]);
        }
    };

    int NT = K >> 6;
    stage(0, 0);
    __syncthreads();                        // implicit vmcnt(0): buf0 ready

    for (int t = 0; t < NT; ++t) {
        int cur = t & 1;
        if (t + 1 < NT) stage(cur ^ 1, (t + 1) * 64);   // hide under compute

        bfrag af[4][2], bf[4][2];
#pragma unroll
        for (int mi = 0; mi < 4; ++mi)
#pragma unroll
            for (int kc = 0; kc < 2; ++kc)
                af[mi][kc] = *(const bfrag*)&sm.s.A[cur][wm + mi * 16 + l15][(((kc * 4 + quad) ^ rsw)) * 8];
#pragma unroll
        for (int ni = 0; ni < 4; ++ni)
#pragma unroll
            for (int kc = 0; kc < 2; ++kc)
                bf[ni][kc] = *(const bfrag*)&sm.s.B[cur][wn + ni * 16 + l15][(((kc * 4 + quad) ^ rsw)) * 8];
#pragma unroll
        for (int kc = 0; kc < 2; ++kc)
#pragma unroll
            for (int mi = 0; mi < 4; ++mi)
#pragma unroll
                for (int ni = 0; ni < 4; ++ni)
                    acc[mi][ni] = __builtin_amdgcn_mfma_f32_16x16x32_bf16(af[mi][kc], bf[ni][kc], acc[mi][ni], 0, 0, 0);

        __syncthreads();                    // drains vmcnt (t+1 staged) + fences buf[cur]
    }

    // epilogue: 4 rounds; round t stages every wave's mi=t subtile (32x128)
#pragma unroll
    for (int t = 0; t < 4; ++t) {
        __syncthreads();
#pragma unroll
        for (int ni = 0; ni < 4; ++ni)
#pragma unroll
            for (int r = 0; r < 4; ++r) {
                int lr = (w >> 1) * 16 + quad * 4 + r;
                int lc = wn + ni * 16 + l15;
                if (outF) sm.ctf[lr][lc] = acc[t][ni][r];
                else      sm.ct [lr][lc] = f2b(acc[t][ni][r]);
            }
        __syncthreads();
        if (outF) {
#pragma unroll
            for (int i = 0; i < 4; ++i) {
                int cc = tid + i * 256;
                int lr = cc >> 5, c4 = (cc & 31) * 4;
                int grow = m0 + (lr >> 4) * 64 + t * 16 + (lr & 15);
                *(float4*)((float*)Cmat + (size_t)grow * N + n0 + c4) =
                    *(const float4*)&sm.ctf[lr][c4];
            }
        } else {
#pragma unroll
            for (int i = 0; i < 2; ++i) {
                int cc = tid + i * 256;
                int lr = cc >> 4, c8 = (cc & 15) * 8;
                int grow = m0 + (lr >> 4) * 64 + t * 16 + (lr & 15);
                *(uint4*)((unsigned short*)Cmat + (size_t)grow * N + n0 + c8) =
                    *(const uint4*)&sm.ct[lr][c8];
            }
        }
    }
}

// ---------------------------------------------------------------------------
// RoPE trig table: tab[t*64 + i1] = (cos, sin) of (pos+t) * 10000^(-2*i1/128),
// i1 in 0..63. Uses the SAME libm exp2f/cosf/sinf as the old in-rope path ->
// bit-identical trig values, zero numerical risk.
// ---------------------------------------------------------------------------
__global__ __launch_bounds__(256) void k_trig(float2* __restrict__ tab,
                                              const int* __restrict__ posPtr) {
    int tid = blockIdx.x * 256 + threadIdx.x;   // 131072 total
    int i1 = tid & 63, t = tid >> 6;
    float p = (float)(*posPtr + t);
    float f = exp2f(-(float)i1 * 0.20762050595278f);
    float th = p * f;
    tab[tid] = make_float2(cosf(th), sinf(th));
}

// ---------------------------------------------------------------------------
// RoPE in-place on bf16 X, table-driven, 2-wide (d and d+1 share the angle).
// Thread handles d = 2*d2, 2*d2+1 (x1 pair) and their +64 partners (x2 pair).
// Bit-identical to the old per-element rope (same operands, same fp32 FMA
// shapes, same f2b rounding).
// ---------------------------------------------------------------------------
__global__ __launch_bounds__(256) void k_rope(unsigned short* __restrict__ X,
                                              const float2* __restrict__ tab,
                                              int lognh, int stride) {
    int tid = blockIdx.x * 256 + threadIdx.x;
    int d2 = tid & 31;
    int nh = 1 << lognh;
    int h = (tid >> 5) & (nh - 1);
    int row = tid >> (5 + lognh);
    int t = row & (TT - 1);
    size_t base = (size_t)row * stride + h * 128 + d2 * 2;
    unsigned int ua = *(const unsigned int*)(X + base);        // x1: d, d+1
    unsigned int ub = *(const unsigned int*)(X + base + 64);   // x2: d+64, d+65
    float x1a = b2f((unsigned short)(ua & 0xffff));
    float x1b = b2f((unsigned short)(ua >> 16));
    float x2a = b2f((unsigned short)(ub & 0xffff));
    float x2b = b2f((unsigned short)(ub >> 16));
    float2 cs1 = tab[t * 64 + d2];
    float2 cs2 = tab[t * 64 + d2 + 32];
    unsigned int o1 = (unsigned int)f2b(x1a * cs1.x - x2a * cs1.y)
                    | ((unsigned int)f2b(x1b * cs1.x - x2b * cs1.y) << 16);
    unsigned int o2 = (unsigned int)f2b(x2a * cs2.x + x1a * cs2.y)
                    | ((unsigned int)f2b(x2b * cs2.x + x1b * cs2.y) << 16);
    *(unsigned int*)(X + base)      = o1;
    *(unsigned int*)(X + base + 64) = o2;
}

// ---------------------------------------------------------------------------
// Flash attention, causal, GQA (16 q / 4 kv heads). 512 threads, QBLK=128,
// paired q-tiles (i, 15-i); double-buffered K/V LDS, one barrier per K-step,
// register prefetch post-barrier; inactive-tile skip; interior fast path;
// T13 defer-max THR=8; swapped QK^T in-lane softmax (round-7 winner).
// NEW: T5 setprio(1) around both MFMA clusters (m191: +4-7% attn).
// ---------------------------------------------------------------------------
__device__ __forceinline__ void flash_pass(
    int qbase, int b, int h, int kvh,
    const unsigned short* __restrict__ QKV,
    const unsigned short* __restrict__ VbT,
    unsigned short* __restrict__ att,
    unsigned short (&Ks)[2][32][136],
    unsigned short (&Vt)[2][128][40],
    unsigned short (&Pt)[8][16][40]) {

    int tid = threadIdx.x;
    int w = tid >> 6, lane = tid & 63, quad = lane >> 4, l15 = lane & 15;

    bfrag qf[4];
    {
        size_t qrow = (size_t)(b * TT + qbase + w * 16 + l15);
        for (int kc = 0; kc < 4; ++kc)
            qf[kc] = *(const bfrag*)(QKV + qrow * 3072 + h * 128 + kc * 32 + quad * 8);
    }

    float mreg = NEG_BIG, lreg = 0.f;      // state for q = qgmin + l15
    facc o[8];
#pragma unroll
    for (int nb2 = 0; nb2 < 8; ++nb2)
#pragma unroll
        for (int r = 0; r < 4; ++r) o[nb2][r] = 0.f;

    int krow = tid >> 4, d8 = (tid & 15) * 8;
    int vd = tid >> 2, tc = (tid & 3) * 8;
    const unsigned short* Kg = QKV + (size_t)(b * TT) * 3072 + 2048 + kvh * 128;
    const unsigned short* Vg = VbT + (size_t)(kvh * 128 + vd) * 8192 + b * TT;

    const float sc = 0.08838834764831845f;   // 1/sqrt(128)
    int kmax = qbase + 128;
    int nt = kmax >> 5;
    int qgmin = qbase + w * 16;
    int myq = qgmin + l15;                   // this lane's q-row

    uint4 rk = *(const uint4*)(Kg + (size_t)krow * 3072 + d8);
    uint4 rv = *(const uint4*)(Vg + tc);

    for (int t = 0; t < nt; ++t) {
        int cur = t & 1;
        int k0 = t * 32;
        *(uint4*)&Ks[cur][krow][d8] = rk;
        *(uint4*)&Vt[cur][vd][tc]   = rv;
        __syncthreads();

        if (t + 1 < nt) {
            int k0n = k0 + 32;
            rk = *(const uint4*)(Kg + (size_t)(k0n + krow) * 3072 + d8);
            rv = *(const uint4*)(Vg + k0n + tc);
        }

        if (k0 > qgmin + 15) continue;       // fully-masked tile for this wave

        // swapped QK^T: A = K-frag, B = Q-frag -> D[k][q], q = l15
        facc s[2];
        __builtin_amdgcn_s_setprio(1);
#pragma unroll
        for (int nb = 0; nb < 2; ++nb) {
#pragma unroll
            for (int r = 0; r < 4; ++r) s[nb][r] = 0.f;
#pragma unroll
            for (int kc = 0; kc < 4; ++kc) {
                bfrag kf = *(const bfrag*)&Ks[cur][nb * 16 + l15][kc * 32 + quad * 8];
                s[nb] = __builtin_amdgcn_mfma_f32_16x16x32_bf16(kf, qf[kc], s[nb], 0, 0, 0);
            }
        }
        __builtin_amdgcn_s_setprio(0);

        bool fullT = (k0 + 31) <= qgmin;
        float v[2][4];
        if (fullT) {
#pragma unroll
            for (int nb = 0; nb < 2; ++nb)
#pragma unroll
                for (int r = 0; r < 4; ++r) v[nb][r] = s[nb][r] * sc;
        } else {
#pragma unroll
            for (int nb = 0; nb < 2; ++nb)
#pragma unroll
                for (int r = 0; r < 4; ++r) {
                    int kg = k0 + nb * 16 + quad * 4 + r;
                    v[nb][r] = (kg > myq) ? NEG_BIG : s[nb][r] * sc;
                }
        }

        // row max: 7 local fmax + 2-step quad fold
        float mx = fmaxf(fmaxf(fmaxf(v[0][0], v[0][1]), fmaxf(v[0][2], v[0][3])),
                         fmaxf(fmaxf(v[1][0], v[1][1]), fmaxf(v[1][2], v[1][3])));
        mx = fmaxf(mx, __shfl_xor(mx, 16, 64));
        mx = fmaxf(mx, __shfl_xor(mx, 32, 64));

        bool need = (mx > mreg + 8.f);       // T13 defer-max, THR=8
        float mnew = need ? mx : mreg;
        float alpha = need ? __expf(mreg - mnew) : 1.f;

        float p[2][4];
        float psum = 0.f;
#pragma unroll
        for (int nb = 0; nb < 2; ++nb)
#pragma unroll
            for (int r = 0; r < 4; ++r) {
                p[nb][r] = __expf(v[nb][r] - mnew);   // exp(-huge)=0 for masked
                psum += p[nb][r];
            }
        psum += __shfl_xor(psum, 16, 64);
        psum += __shfl_xor(psum, 32, 64);
        lreg = lreg * alpha + psum;
        mreg = mnew;

        // P -> LDS: lane writes 4 contiguous k per nb (8B each)
#pragma unroll
        for (int nb = 0; nb < 2; ++nb) {
            unsigned short pk[4];
#pragma unroll
            for (int r = 0; r < 4; ++r) pk[r] = f2b(p[nb][r]);
            *(uint2*)&Pt[w][l15][nb * 16 + quad * 4] = *(const uint2*)pk;
        }

        if (__any(need)) {                   // fetch per-q alpha, rescale o
#pragma unroll
            for (int r = 0; r < 4; ++r) {
                float al = __shfl(alpha, quad * 4 + r, 16);
#pragma unroll
                for (int nb2 = 0; nb2 < 8; ++nb2) o[nb2][r] *= al;
            }
        }

        asm volatile("s_waitcnt lgkmcnt(0)" ::: "memory");   // wave-local RAW on Pt[w]
        bfrag pf = *(const bfrag*)&Pt[w][l15][quad * 8];
        __builtin_amdgcn_s_setprio(1);
#pragma unroll
        for (int nb2 = 0; nb2 < 8; ++nb2) {
            bfrag vf = *(const bfrag*)&Vt[cur][nb2 * 16 + l15][quad * 8];
            o[nb2] = __builtin_amdgcn_mfma_f32_16x16x32_bf16(pf, vf, o[nb2], 0, 0, 0);
        }
        __builtin_amdgcn_s_setprio(0);
    }

    // final: fetch per-q l via width-16 shfl, divide, store
    float lr[4];
#pragma unroll
    for (int r = 0; r < 4; ++r) lr[r] = __shfl(lreg, quad * 4 + r, 16);
#pragma unroll
    for (int nb2 = 0; nb2 < 8; ++nb2)
#pragma unroll
        for (int r = 0; r < 4; ++r) {
            int qg = qbase + w * 16 + quad * 4 + r;
            att[(size_t)(b * TT + qg) * 2048 + h * 128 + nb2 * 16 + l15] =
                f2b(o[nb2][r] / lr[r]);
        }
}

__global__ __launch_bounds__(512, 4) void k_flash(const unsigned short* __restrict__ QKV,
                                                  const unsigned short* __restrict__ VbT,
                                                  unsigned short* __restrict__ att) {
    __shared__ alignas(16) unsigned short Ks[2][32][136];
    __shared__ alignas(16) unsigned short Vt[2][128][40];
    __shared__ alignas(16) unsigned short Pt[8][16][40];
    int bh = blockIdx.y;
    int b = bh >> 4, h = bh & 15;
    int kvh = h >> 2;
    int i = blockIdx.x;

    flash_pass(i * 128, b, h, kvh, QKV, VbT, att, Ks, Vt, Pt);
    __syncthreads();
    flash_pass((15 - i) * 128, b, h, kvh, QKV, VbT, att, Ks, Vt, Pt);
}

// ---------------------------------------------------------------------------
extern "C" void kernel_launch(void* const* d_in, const int* in_sizes, int n_in,
                              void* d_out, int out_size, void* d_ws, size_t ws_size,
                              hipStream_t stream) {
    const float* x  = (const float*)d_in[0];
    const float* Wq = (const float*)d_in[1];
    const float* Wk = (const float*)d_in[2];
    const float* Wv = (const float*)d_in[3];
    const float* Wo = (const float*)d_in[4];
    const int* pos  = (const int*)d_in[5];

    char* ws = (char*)d_ws;
    unsigned short* xb   = (unsigned short*)(ws + 0);          // 32 MB (8192x2048); reused as att out
    unsigned short* QKV  = (unsigned short*)(ws + 33554432);   // 48 MB (8192x3072)
    unsigned short* VbT  = (unsigned short*)(ws + 83886080);   //  8 MB (512x8192)
    unsigned short* WqT  = (unsigned short*)(ws + 92274688);   //  8 MB (2048x2048)
    unsigned short* WkvT = (unsigned short*)(ws + 100663296);  //  4 MB (1024x2048) -- contiguous with WqT
    unsigned short* WoT  = (unsigned short*)(ws + 104857600);  //  8 MB
    float2*         tab  = (float2*)(ws + 113246208);          //  1 MB rope trig table -> 114.25 MB

    // trig table (independent of everything; launch first)
    k_trig<<<512, 256, 0, stream>>>(tab, pos);

    // bf16 conversion + weight transposes (WqT|WkvT form one contiguous 3072x2048 Bt)
    k_cvt<<<8192, 256, 0, stream>>>(x, xb, 2097152);
    k_wt<<<dim3(32, 32), 256, 0, stream>>>(Wq, WqT, 2048);
    k_wt<<<dim3(8, 32),  256, 0, stream>>>(Wk, WkvT, 512);
    k_wt<<<dim3(8, 32),  256, 0, stream>>>(Wv, WkvT + (size_t)512 * 2048, 512);
    k_wt<<<dim3(32, 32), 256, 0, stream>>>(Wo, WoT, 2048);

    // fused Q|K|V projection: 2-phase, st_16x32 swizzle (experimental arm)
    k_gemm2ph<1><<<dim3(24, 64), 256, 0, stream>>>(xb, WqT, QKV, 8192, 3072, 2048, 0);

    // RoPE, table-driven (Q: 16 heads, cols 0..2047; K: 4 heads, cols 2048..2559)
    k_rope<<<16384, 256, 0, stream>>>(QKV, tab, 4, 3072);
    k_rope<<<4096,  256, 0, stream>>>(QKV + 2048, tab, 2, 3072);

    // V transpose for flash B-frag staging
    k_vt<<<dim3(8, 128), 256, 0, stream>>>(QKV, VbT);

    // causal GQA flash attention (swapped-QK softmax + setprio) -> xb
    k_flash<<<dim3(8, 64), 512, 0, stream>>>(QKV, VbT, xb);

    // output projection -> fp32 d_out: 2-phase, old swizzle (control arm)
    k_gemm2ph<0><<<dim3(16, 64), 256, 0, stream>>>(xb, WoT, d_out, 8192, 2048, 2048, 1);
}

// Round 9
// 623.558 us; speedup vs baseline: 1.0923x; 1.0923x over previous
//
#include <hip/hip_runtime.h>
#include <math.h>

#define TT 2048

typedef __attribute__((ext_vector_type(8))) short bfrag;   // 8 bf16 in 4 VGPRs
typedef __attribute__((ext_vector_type(4))) float facc;    // 4 fp32 acc

#define NEG_BIG (-1.0e30f)

typedef __attribute__((address_space(1))) const void gas_void;
typedef __attribute__((address_space(3))) void las_void;

__device__ __forceinline__ void gl_lds16(const void* g, void* l) {
    __builtin_amdgcn_global_load_lds((gas_void*)g, (las_void*)l, 16, 0, 0);
}

__device__ __forceinline__ unsigned short f2b(float f) {
    union { float f; unsigned int i; } v; v.f = f;
    unsigned int b = v.i;
    return (unsigned short)((b + 0x7FFFu + ((b >> 16) & 1u)) >> 16);  // RNE
}
__device__ __forceinline__ float b2f(unsigned short s) {
    union { unsigned int i; float f; } u; u.i = ((unsigned int)s) << 16; return u.f;
}
__device__ __forceinline__ void cvt8_f32(const float* __restrict__ p, unsigned short* d) {
    float4 lo = *(const float4*)p, hi = *(const float4*)(p + 4);
    d[0] = f2b(lo.x); d[1] = f2b(lo.y); d[2] = f2b(lo.z); d[3] = f2b(lo.w);
    d[4] = f2b(hi.x); d[5] = f2b(hi.y); d[6] = f2b(hi.z); d[7] = f2b(hi.w);
}

// ---------------------------------------------------------------------------
// fp32 -> bf16 flat convert (n8 = count of 8-element chunks)
// ---------------------------------------------------------------------------
__global__ __launch_bounds__(256) void k_cvt(const float* __restrict__ in,
                                             unsigned short* __restrict__ out, int n8) {
    int c = blockIdx.x * 256 + threadIdx.x;
    if (c < n8) {
        unsigned short t[8];
        cvt8_f32(in + (size_t)c * 8, t);
        *(uint4*)(out + (size_t)c * 8) = *(const uint4*)t;
    }
}

// ---------------------------------------------------------------------------
// Weight transpose+convert: W (2048 x N fp32, row-major) -> WT (N x 2048 bf16)
// ---------------------------------------------------------------------------
__global__ __launch_bounds__(256) void k_wt(const float* __restrict__ W,
                                            unsigned short* __restrict__ WT, int N) {
    __shared__ alignas(16) unsigned short tile[64][72];
    int r0 = blockIdx.y * 64, c0 = blockIdx.x * 64;
    int tid = threadIdx.x;
    for (int i = 0; i < 2; ++i) {
        int c = tid + i * 256;
        int row = c >> 3, c8 = (c & 7) * 8;
        unsigned short t[8];
        cvt8_f32(W + (size_t)(r0 + row) * N + c0 + c8, t);
        *(uint4*)&tile[row][c8] = *(const uint4*)t;
    }
    __syncthreads();
    for (int i = 0; i < 2; ++i) {
        int c = tid + i * 256;
        int col = c >> 3, r8 = (c & 7) * 8;
        unsigned short t[8];
        for (int j = 0; j < 8; ++j) t[j] = tile[r8 + j][col];
        *(uint4*)(WT + (size_t)(c0 + col) * 2048 + r0 + r8) = *(const uint4*)t;
    }
}

// ---------------------------------------------------------------------------
// V transpose: QKV (8192 x 3072 bf16, V = cols 2560..3071) -> VbT (512 x 8192)
// ---------------------------------------------------------------------------
__global__ __launch_bounds__(256) void k_vt(const unsigned short* __restrict__ QKV,
                                            unsigned short* __restrict__ VbT) {
    __shared__ alignas(16) unsigned short tile[64][72];
    int r0 = blockIdx.y * 64, c0 = blockIdx.x * 64;
    int tid = threadIdx.x;
    for (int i = 0; i < 2; ++i) {
        int c = tid + i * 256;
        int row = c >> 3, c8 = (c & 7) * 8;
        *(uint4*)&tile[row][c8] =
            *(const uint4*)(QKV + (size_t)(r0 + row) * 3072 + 2560 + c0 + c8);
    }
    __syncthreads();
    for (int i = 0; i < 2; ++i) {
        int c = tid + i * 256;
        int col = c >> 3, r8 = (c & 7) * 8;
        unsigned short t[8];
        for (int j = 0; j < 8; ++j) t[j] = tile[r8 + j][col];
        *(uint4*)(VbT + (size_t)(c0 + col) * 8192 + r0 + r8) = *(const uint4*)t;
    }
}

// ---------------------------------------------------------------------------
// 2-phase double-buffered m97 GEMM (round-6/7 winner), swizzle LOCKED to the
// full 3-bit XOR (round-8 A/B: st_16x32-style collapsed slot diversity 8->4
// and doubled conflicts; with 128B rows bank=f(16B slot) so 8 slots x 8
// lanes is the structural floor, which SWZ=0 achieves).
// NEW: T1 bijective XCD swizzle -- consecutive by-panels land on one XCD's
// L2 -> A-panel reuse (falsifiable: FETCH_SIZE 153 MB -> ~125-135 MB).
// ---------------------------------------------------------------------------
__global__ __launch_bounds__(256) void k_gemm2ph(const unsigned short* __restrict__ A,
                                                 const unsigned short* __restrict__ Bt,
                                                 void* __restrict__ Cmat,
                                                 int M, int N, int K, int outF) {
    __shared__ union SM {
        struct { unsigned short A[2][128][64]; unsigned short B[2][128][64]; } s;  // 64 KB
        unsigned short ct[32][136];
        float          ctf[32][136];
    } sm;
    int tid = threadIdx.x;
    int w = tid >> 6, lane = tid & 63, quad = lane >> 4, l15 = lane & 15;

    // T1: bijective XCD swizzle (nwg % 8 == 0 for both grids here)
    int gx = gridDim.x;
    int nwg = gx * gridDim.y;
    int bid = blockIdx.y * gx + blockIdx.x;
    int cpx = nwg >> 3;
    int sid = (bid & 7) * cpx + (bid >> 3);
    int m0 = (sid / gx) * 128, n0 = (sid % gx) * 128;

    int wm = (w >> 1) * 64, wn = (w & 1) * 64;

    int srow   = lane >> 3;                 // 0..7
    int schunk = (lane & 7) ^ (lane >> 3);  // inverse-swizzled source chunk

    facc acc[4][4];
#pragma unroll
    for (int mi = 0; mi < 4; ++mi)
#pragma unroll
        for (int ni = 0; ni < 4; ++ni)
#pragma unroll
            for (int r = 0; r < 4; ++r) acc[mi][ni][r] = 0.f;

    auto stage = [&](int bb, int k0) {
#pragma unroll
        for (int i = 0; i < 4; ++i) {
            int row = w * 32 + i * 8;
            gl_lds16(A  + (size_t)(m0 + row + srow) * K + k0 + schunk * 8, &sm.s.A[bb][row][0]);
            gl_lds16(Bt + (size_t)(n0 + row + srow) * K + k0 + schunk * 8, &sm.s.B[bb][row][0]);
        }
    };

    int NT = K >> 6;
    stage(0, 0);
    __syncthreads();                        // implicit vmcnt(0): buf0 ready

    for (int t = 0; t < NT; ++t) {
        int cur = t & 1;
        if (t + 1 < NT) stage(cur ^ 1, (t + 1) * 64);   // hide under compute

        bfrag af[4][2], bf[4][2];
#pragma unroll
        for (int mi = 0; mi < 4; ++mi)
#pragma unroll
            for (int kc = 0; kc < 2; ++kc)
                af[mi][kc] = *(const bfrag*)&sm.s.A[cur][wm + mi * 16 + l15][((kc * 4 + quad) ^ (l15 & 7)) * 8];
#pragma unroll
        for (int ni = 0; ni < 4; ++ni)
#pragma unroll
            for (int kc = 0; kc < 2; ++kc)
                bf[ni][kc] = *(const bfrag*)&sm.s.B[cur][wn + ni * 16 + l15][((kc * 4 + quad) ^ (l15 & 7)) * 8];
#pragma unroll
        for (int kc = 0; kc < 2; ++kc)
#pragma unroll
            for (int mi = 0; mi < 4; ++mi)
#pragma unroll
                for (int ni = 0; ni < 4; ++ni)
                    acc[mi][ni] = __builtin_amdgcn_mfma_f32_16x16x32_bf16(af[mi][kc], bf[ni][kc], acc[mi][ni], 0, 0, 0);

        __syncthreads();                    // drains vmcnt (t+1 staged) + fences buf[cur]
    }

    // epilogue: 4 rounds; round t stages every wave's mi=t subtile (32x128)
#pragma unroll
    for (int t = 0; t < 4; ++t) {
        __syncthreads();
#pragma unroll
        for (int ni = 0; ni < 4; ++ni)
#pragma unroll
            for (int r = 0; r < 4; ++r) {
                int lr = (w >> 1) * 16 + quad * 4 + r;
                int lc = wn + ni * 16 + l15;
                if (outF) sm.ctf[lr][lc] = acc[t][ni][r];
                else      sm.ct [lr][lc] = f2b(acc[t][ni][r]);
            }
        __syncthreads();
        if (outF) {
#pragma unroll
            for (int i = 0; i < 4; ++i) {
                int cc = tid + i * 256;
                int lr = cc >> 5, c4 = (cc & 31) * 4;
                int grow = m0 + (lr >> 4) * 64 + t * 16 + (lr & 15);
                *(float4*)((float*)Cmat + (size_t)grow * N + n0 + c4) =
                    *(const float4*)&sm.ctf[lr][c4];
            }
        } else {
#pragma unroll
            for (int i = 0; i < 2; ++i) {
                int cc = tid + i * 256;
                int lr = cc >> 4, c8 = (cc & 15) * 8;
                int grow = m0 + (lr >> 4) * 64 + t * 16 + (lr & 15);
                *(uint4*)((unsigned short*)Cmat + (size_t)grow * N + n0 + c8) =
                    *(const uint4*)&sm.ct[lr][c8];
            }
        }
    }
}

// ---------------------------------------------------------------------------
// RoPE trig table: tab[t*64 + i1] = (cos, sin) of (pos+t) * 10000^(-2*i1/128).
// Same libm calls as the original in-rope path -> bit-identical trig values.
// ---------------------------------------------------------------------------
__global__ __launch_bounds__(256) void k_trig(float2* __restrict__ tab,
                                              const int* __restrict__ posPtr) {
    int tid = blockIdx.x * 256 + threadIdx.x;   // 131072 total
    int i1 = tid & 63, t = tid >> 6;
    float p = (float)(*posPtr + t);
    float f = exp2f(-(float)i1 * 0.20762050595278f);
    float th = p * f;
    tab[tid] = make_float2(cosf(th), sinf(th));
}

// ---------------------------------------------------------------------------
// RoPE in-place on bf16 X, table-driven, 2-wide (d and d+1 share the angle).
// ---------------------------------------------------------------------------
__global__ __launch_bounds__(256) void k_rope(unsigned short* __restrict__ X,
                                              const float2* __restrict__ tab,
                                              int lognh, int stride) {
    int tid = blockIdx.x * 256 + threadIdx.x;
    int d2 = tid & 31;
    int nh = 1 << lognh;
    int h = (tid >> 5) & (nh - 1);
    int row = tid >> (5 + lognh);
    int t = row & (TT - 1);
    size_t base = (size_t)row * stride + h * 128 + d2 * 2;
    unsigned int ua = *(const unsigned int*)(X + base);        // x1: d, d+1
    unsigned int ub = *(const unsigned int*)(X + base + 64);   // x2: d+64, d+65
    float x1a = b2f((unsigned short)(ua & 0xffff));
    float x1b = b2f((unsigned short)(ua >> 16));
    float x2a = b2f((unsigned short)(ub & 0xffff));
    float x2b = b2f((unsigned short)(ub >> 16));
    float2 cs1 = tab[t * 64 + d2];
    float2 cs2 = tab[t * 64 + d2 + 32];
    unsigned int o1 = (unsigned int)f2b(x1a * cs1.x - x2a * cs1.y)
                    | ((unsigned int)f2b(x1b * cs1.x - x2b * cs1.y) << 16);
    unsigned int o2 = (unsigned int)f2b(x2a * cs2.x + x1a * cs2.y)
                    | ((unsigned int)f2b(x2b * cs2.x + x1b * cs2.y) << 16);
    *(unsigned int*)(X + base)      = o1;
    *(unsigned int*)(X + base + 64) = o2;
}

// ---------------------------------------------------------------------------
// Flash attention, causal, GQA. 512 threads, QBLK=128, paired q-tiles
// (i, 15-i); double-buffered K/V LDS, one barrier per K-step, register
// prefetch post-barrier; inactive-tile skip; interior fast path; T13
// defer-max THR=8; swapped QK^T in-lane softmax (round-7 winner).
// PRIO template = within-run A/B of T5 setprio (round-8 added it blind to a
// barrier-lockstep kernel where m190 measured it negative on GEMM).
// ---------------------------------------------------------------------------
template <int PRIO>
__device__ __forceinline__ void flash_pass(
    int qbase, int b, int h, int kvh,
    const unsigned short* __restrict__ QKV,
    const unsigned short* __restrict__ VbT,
    unsigned short* __restrict__ att,
    unsigned short (&Ks)[2][32][136],
    unsigned short (&Vt)[2][128][40],
    unsigned short (&Pt)[8][16][40]) {

    int tid = threadIdx.x;
    int w = tid >> 6, lane = tid & 63, quad = lane >> 4, l15 = lane & 15;

    bfrag qf[4];
    {
        size_t qrow = (size_t)(b * TT + qbase + w * 16 + l15);
        for (int kc = 0; kc < 4; ++kc)
            qf[kc] = *(const bfrag*)(QKV + qrow * 3072 + h * 128 + kc * 32 + quad * 8);
    }

    float mreg = NEG_BIG, lreg = 0.f;      // state for q = qgmin + l15
    facc o[8];
#pragma unroll
    for (int nb2 = 0; nb2 < 8; ++nb2)
#pragma unroll
        for (int r = 0; r < 4; ++r) o[nb2][r] = 0.f;

    int krow = tid >> 4, d8 = (tid & 15) * 8;
    int vd = tid >> 2, tc = (tid & 3) * 8;
    const unsigned short* Kg = QKV + (size_t)(b * TT) * 3072 + 2048 + kvh * 128;
    const unsigned short* Vg = VbT + (size_t)(kvh * 128 + vd) * 8192 + b * TT;

    const float sc = 0.08838834764831845f;   // 1/sqrt(128)
    int kmax = qbase + 128;
    int nt = kmax >> 5;
    int qgmin = qbase + w * 16;
    int myq = qgmin + l15;                   // this lane's q-row

    uint4 rk = *(const uint4*)(Kg + (size_t)krow * 3072 + d8);
    uint4 rv = *(const uint4*)(Vg + tc);

    for (int t = 0; t < nt; ++t) {
        int cur = t & 1;
        int k0 = t * 32;
        *(uint4*)&Ks[cur][krow][d8] = rk;
        *(uint4*)&Vt[cur][vd][tc]   = rv;
        __syncthreads();

        if (t + 1 < nt) {
            int k0n = k0 + 32;
            rk = *(const uint4*)(Kg + (size_t)(k0n + krow) * 3072 + d8);
            rv = *(const uint4*)(Vg + k0n + tc);
        }

        if (k0 > qgmin + 15) continue;       // fully-masked tile for this wave

        // swapped QK^T: A = K-frag, B = Q-frag -> D[k][q], q = l15
        facc s[2];
        if constexpr (PRIO) __builtin_amdgcn_s_setprio(1);
#pragma unroll
        for (int nb = 0; nb < 2; ++nb) {
#pragma unroll
            for (int r = 0; r < 4; ++r) s[nb][r] = 0.f;
#pragma unroll
            for (int kc = 0; kc < 4; ++kc) {
                bfrag kf = *(const bfrag*)&Ks[cur][nb * 16 + l15][kc * 32 + quad * 8];
                s[nb] = __builtin_amdgcn_mfma_f32_16x16x32_bf16(kf, qf[kc], s[nb], 0, 0, 0);
            }
        }
        if constexpr (PRIO) __builtin_amdgcn_s_setprio(0);

        bool fullT = (k0 + 31) <= qgmin;
        float v[2][4];
        if (fullT) {
#pragma unroll
            for (int nb = 0; nb < 2; ++nb)
#pragma unroll
                for (int r = 0; r < 4; ++r) v[nb][r] = s[nb][r] * sc;
        } else {
#pragma unroll
            for (int nb = 0; nb < 2; ++nb)
#pragma unroll
                for (int r = 0; r < 4; ++r) {
                    int kg = k0 + nb * 16 + quad * 4 + r;
                    v[nb][r] = (kg > myq) ? NEG_BIG : s[nb][r] * sc;
                }
        }

        // row max: 7 local fmax + 2-step fold
        float mx = fmaxf(fmaxf(fmaxf(v[0][0], v[0][1]), fmaxf(v[0][2], v[0][3])),
                         fmaxf(fmaxf(v[1][0], v[1][1]), fmaxf(v[1][2], v[1][3])));
        mx = fmaxf(mx, __shfl_xor(mx, 16, 64));
        mx = fmaxf(mx, __shfl_xor(mx, 32, 64));

        bool need = (mx > mreg + 8.f);       // T13 defer-max, THR=8
        float mnew = need ? mx : mreg;
        float alpha = need ? __expf(mreg - mnew) : 1.f;

        float p[2][4];
        float psum = 0.f;
#pragma unroll
        for (int nb = 0; nb < 2; ++nb)
#pragma unroll
            for (int r = 0; r < 4; ++r) {
                p[nb][r] = __expf(v[nb][r] - mnew);   // exp(-huge)=0 for masked
                psum += p[nb][r];
            }
        psum += __shfl_xor(psum, 16, 64);
        psum += __shfl_xor(psum, 32, 64);
        lreg = lreg * alpha + psum;
        mreg = mnew;

        // P -> LDS: lane writes 4 contiguous k per nb (8B each)
#pragma unroll
        for (int nb = 0; nb < 2; ++nb) {
            unsigned short pk[4];
#pragma unroll
            for (int r = 0; r < 4; ++r) pk[r] = f2b(p[nb][r]);
            *(uint2*)&Pt[w][l15][nb * 16 + quad * 4] = *(const uint2*)pk;
        }

        if (__any(need)) {                   // fetch per-q alpha, rescale o
#pragma unroll
            for (int r = 0; r < 4; ++r) {
                float al = __shfl(alpha, quad * 4 + r, 16);
#pragma unroll
                for (int nb2 = 0; nb2 < 8; ++nb2) o[nb2][r] *= al;
            }
        }

        asm volatile("s_waitcnt lgkmcnt(0)" ::: "memory");   // wave-local RAW on Pt[w]
        bfrag pf = *(const bfrag*)&Pt[w][l15][quad * 8];
        if constexpr (PRIO) __builtin_amdgcn_s_setprio(1);
#pragma unroll
        for (int nb2 = 0; nb2 < 8; ++nb2) {
            bfrag vf = *(const bfrag*)&Vt[cur][nb2 * 16 + l15][quad * 8];
            o[nb2] = __builtin_amdgcn_mfma_f32_16x16x32_bf16(pf, vf, o[nb2], 0, 0, 0);
        }
        if constexpr (PRIO) __builtin_amdgcn_s_setprio(0);
    }

    // final: fetch per-q l via width-16 shfl, divide, store
    float lr[4];
#pragma unroll
    for (int r = 0; r < 4; ++r) lr[r] = __shfl(lreg, quad * 4 + r, 16);
#pragma unroll
    for (int nb2 = 0; nb2 < 8; ++nb2)
#pragma unroll
        for (int r = 0; r < 4; ++r) {
            int qg = qbase + w * 16 + quad * 4 + r;
            att[(size_t)(b * TT + qg) * 2048 + h * 128 + nb2 * 16 + l15] =
                f2b(o[nb2][r] / lr[r]);
        }
}

template <int PRIO>
__global__ __launch_bounds__(512, 4) void k_flash(const unsigned short* __restrict__ QKV,
                                                  const unsigned short* __restrict__ VbT,
                                                  unsigned short* __restrict__ att,
                                                  int ybase) {
    __shared__ alignas(16) unsigned short Ks[2][32][136];
    __shared__ alignas(16) unsigned short Vt[2][128][40];
    __shared__ alignas(16) unsigned short Pt[8][16][40];
    int bh = blockIdx.y + ybase;
    int b = bh >> 4, h = bh & 15;
    int kvh = h >> 2;
    int i = blockIdx.x;

    flash_pass<PRIO>(i * 128, b, h, kvh, QKV, VbT, att, Ks, Vt, Pt);
    __syncthreads();
    flash_pass<PRIO>((15 - i) * 128, b, h, kvh, QKV, VbT, att, Ks, Vt, Pt);
}

// ---------------------------------------------------------------------------
extern "C" void kernel_launch(void* const* d_in, const int* in_sizes, int n_in,
                              void* d_out, int out_size, void* d_ws, size_t ws_size,
                              hipStream_t stream) {
    const float* x  = (const float*)d_in[0];
    const float* Wq = (const float*)d_in[1];
    const float* Wk = (const float*)d_in[2];
    const float* Wv = (const float*)d_in[3];
    const float* Wo = (const float*)d_in[4];
    const int* pos  = (const int*)d_in[5];

    char* ws = (char*)d_ws;
    unsigned short* xb   = (unsigned short*)(ws + 0);          // 32 MB (8192x2048); reused as att out
    unsigned short* QKV  = (unsigned short*)(ws + 33554432);   // 48 MB (8192x3072)
    unsigned short* VbT  = (unsigned short*)(ws + 83886080);   //  8 MB (512x8192)
    unsigned short* WqT  = (unsigned short*)(ws + 92274688);   //  8 MB (2048x2048)
    unsigned short* WkvT = (unsigned short*)(ws + 100663296);  //  4 MB (1024x2048) -- contiguous with WqT
    unsigned short* WoT  = (unsigned short*)(ws + 104857600);  //  8 MB
    float2*         tab  = (float2*)(ws + 113246208);          //  1 MB rope trig table -> 114.25 MB

    // trig table (independent of everything; launch first)
    k_trig<<<512, 256, 0, stream>>>(tab, pos);

    // bf16 conversion + weight transposes (WqT|WkvT form one contiguous 3072x2048 Bt)
    k_cvt<<<8192, 256, 0, stream>>>(x, xb, 2097152);
    k_wt<<<dim3(32, 32), 256, 0, stream>>>(Wq, WqT, 2048);
    k_wt<<<dim3(8, 32),  256, 0, stream>>>(Wk, WkvT, 512);
    k_wt<<<dim3(8, 32),  256, 0, stream>>>(Wv, WkvT + (size_t)512 * 2048, 512);
    k_wt<<<dim3(32, 32), 256, 0, stream>>>(Wo, WoT, 2048);

    // fused Q|K|V projection: 2-phase, locked swizzle + T1 XCD swizzle
    k_gemm2ph<<<dim3(24, 64), 256, 0, stream>>>(xb, WqT, QKV, 8192, 3072, 2048, 0);

    // RoPE, table-driven (Q: 16 heads, cols 0..2047; K: 4 heads, cols 2048..2559)
    k_rope<<<16384, 256, 0, stream>>>(QKV, tab, 4, 3072);
    k_rope<<<4096,  256, 0, stream>>>(QKV + 2048, tab, 2, 3072);

    // V transpose for flash B-frag staging
    k_vt<<<dim3(8, 128), 256, 0, stream>>>(QKV, VbT);

    // causal GQA flash attention -> xb; PRIO A/B split across the bh grid
    k_flash<0><<<dim3(8, 32), 512, 0, stream>>>(QKV, VbT, xb, 0);
    k_flash<1><<<dim3(8, 32), 512, 0, stream>>>(QKV, VbT, xb, 32);

    // output projection -> fp32 d_out: 2-phase, locked swizzle + T1
    k_gemm2ph<<<dim3(16, 64), 256, 0, stream>>>(xb, WoT, d_out, 8192, 2048, 2048, 1);
}

// Round 10
// 578.083 us; speedup vs baseline: 1.1782x; 1.0787x over previous
//
#include <hip/hip_runtime.h>
#include <math.h>

#define TT 2048

typedef __attribute__((ext_vector_type(8))) short bfrag;   // 8 bf16 in 4 VGPRs
typedef __attribute__((ext_vector_type(4))) float facc;    // 4 fp32 acc

#define NEG_BIG (-1.0e30f)

typedef __attribute__((address_space(1))) const void gas_void;
typedef __attribute__((address_space(3))) void las_void;

__device__ __forceinline__ void gl_lds16(const void* g, void* l) {
    __builtin_amdgcn_global_load_lds((gas_void*)g, (las_void*)l, 16, 0, 0);
}

__device__ __forceinline__ unsigned short f2b(float f) {
    union { float f; unsigned int i; } v; v.f = f;
    unsigned int b = v.i;
    return (unsigned short)((b + 0x7FFFu + ((b >> 16) & 1u)) >> 16);  // RNE
}
__device__ __forceinline__ float b2f(unsigned short s) {
    union { unsigned int i; float f; } u; u.i = ((unsigned int)s) << 16; return u.f;
}
__device__ __forceinline__ void cvt8_f32(const float* __restrict__ p, unsigned short* d) {
    float4 lo = *(const float4*)p, hi = *(const float4*)(p + 4);
    d[0] = f2b(lo.x); d[1] = f2b(lo.y); d[2] = f2b(lo.z); d[3] = f2b(lo.w);
    d[4] = f2b(hi.x); d[5] = f2b(hi.y); d[6] = f2b(hi.z); d[7] = f2b(hi.w);
}

// ---------------------------------------------------------------------------
// fp32 -> bf16 flat convert (n8 = count of 8-element chunks)
// ---------------------------------------------------------------------------
__global__ __launch_bounds__(256) void k_cvt(const float* __restrict__ in,
                                             unsigned short* __restrict__ out, int n8) {
    int c = blockIdx.x * 256 + threadIdx.x;
    if (c < n8) {
        unsigned short t[8];
        cvt8_f32(in + (size_t)c * 8, t);
        *(uint4*)(out + (size_t)c * 8) = *(const uint4*)t;
    }
}

// ---------------------------------------------------------------------------
// Weight transpose+convert: W (2048 x N fp32, row-major) -> WT (N x 2048 bf16)
// ---------------------------------------------------------------------------
__global__ __launch_bounds__(256) void k_wt(const float* __restrict__ W,
                                            unsigned short* __restrict__ WT, int N) {
    __shared__ alignas(16) unsigned short tile[64][72];
    int r0 = blockIdx.y * 64, c0 = blockIdx.x * 64;
    int tid = threadIdx.x;
    for (int i = 0; i < 2; ++i) {
        int c = tid + i * 256;
        int row = c >> 3, c8 = (c & 7) * 8;
        unsigned short t[8];
        cvt8_f32(W + (size_t)(r0 + row) * N + c0 + c8, t);
        *(uint4*)&tile[row][c8] = *(const uint4*)t;
    }
    __syncthreads();
    for (int i = 0; i < 2; ++i) {
        int c = tid + i * 256;
        int col = c >> 3, r8 = (c & 7) * 8;
        unsigned short t[8];
        for (int j = 0; j < 8; ++j) t[j] = tile[r8 + j][col];
        *(uint4*)(WT + (size_t)(c0 + col) * 2048 + r0 + r8) = *(const uint4*)t;
    }
}

// ---------------------------------------------------------------------------
// V transpose: QKV (8192 x 3072 bf16, V = cols 2560..3071) -> VbT (512 x 8192)
// ---------------------------------------------------------------------------
__global__ __launch_bounds__(256) void k_vt(const unsigned short* __restrict__ QKV,
                                            unsigned short* __restrict__ VbT) {
    __shared__ alignas(16) unsigned short tile[64][72];
    int r0 = blockIdx.y * 64, c0 = blockIdx.x * 64;
    int tid = threadIdx.x;
    for (int i = 0; i < 2; ++i) {
        int c = tid + i * 256;
        int row = c >> 3, c8 = (c & 7) * 8;
        *(uint4*)&tile[row][c8] =
            *(const uint4*)(QKV + (size_t)(r0 + row) * 3072 + 2560 + c0 + c8);
    }
    __syncthreads();
    for (int i = 0; i < 2; ++i) {
        int c = tid + i * 256;
        int col = c >> 3, r8 = (c & 7) * 8;
        unsigned short t[8];
        for (int j = 0; j < 8; ++j) t[j] = tile[r8 + j][col];
        *(uint4*)(VbT + (size_t)(c0 + col) * 8192 + r0 + r8) = *(const uint4*)t;
    }
}

// ---------------------------------------------------------------------------
// 2-phase double-buffered m97 GEMM -- CONSOLIDATED best-known config:
//   - linear block mapping (round-9 A/B: XCD swizzle RAISED fetch 153->168 MB
//     and cost +11 us; with linear dispatch the 8 XCDs advance through the
//     same m-panels concurrently and L3 serves the shared B-panels)
//   - full 3-bit XOR chunk swizzle (round-8 A/B: the structural floor is
//     8 slots x 8 lanes; st_16x32-style halved slot diversity -> 2x conflicts)
//   - BK=64, 64 KB LDS dbuf, stage(t+1) issued before compute(t), ONE
//     __syncthreads per K-tile (round-6/7 winner: 560 TF on QKV)
// ---------------------------------------------------------------------------
__global__ __launch_bounds__(256) void k_gemm2ph(const unsigned short* __restrict__ A,
                                                 const unsigned short* __restrict__ Bt,
                                                 void* __restrict__ Cmat,
                                                 int M, int N, int K, int outF) {
    __shared__ union SM {
        struct { unsigned short A[2][128][64]; unsigned short B[2][128][64]; } s;  // 64 KB
        unsigned short ct[32][136];
        float          ctf[32][136];
    } sm;
    int tid = threadIdx.x;
    int w = tid >> 6, lane = tid & 63, quad = lane >> 4, l15 = lane & 15;
    int m0 = blockIdx.y * 128, n0 = blockIdx.x * 128;
    int wm = (w >> 1) * 64, wn = (w & 1) * 64;

    int srow   = lane >> 3;                 // 0..7
    int schunk = (lane & 7) ^ (lane >> 3);  // inverse-swizzled source chunk

    facc acc[4][4];
#pragma unroll
    for (int mi = 0; mi < 4; ++mi)
#pragma unroll
        for (int ni = 0; ni < 4; ++ni)
#pragma unroll
            for (int r = 0; r < 4; ++r) acc[mi][ni][r] = 0.f;

    auto stage = [&](int bb, int k0) {
#pragma unroll
        for (int i = 0; i < 4; ++i) {
            int row = w * 32 + i * 8;
            gl_lds16(A  + (size_t)(m0 + row + srow) * K + k0 + schunk * 8, &sm.s.A[bb][row][0]);
            gl_lds16(Bt + (size_t)(n0 + row + srow) * K + k0 + schunk * 8, &sm.s.B[bb][row][0]);
        }
    };

    int NT = K >> 6;
    stage(0, 0);
    __syncthreads();                        // implicit vmcnt(0): buf0 ready

    for (int t = 0; t < NT; ++t) {
        int cur = t & 1;
        if (t + 1 < NT) stage(cur ^ 1, (t + 1) * 64);   // hide under compute

        bfrag af[4][2], bf[4][2];
#pragma unroll
        for (int mi = 0; mi < 4; ++mi)
#pragma unroll
            for (int kc = 0; kc < 2; ++kc)
                af[mi][kc] = *(const bfrag*)&sm.s.A[cur][wm + mi * 16 + l15][((kc * 4 + quad) ^ (l15 & 7)) * 8];
#pragma unroll
        for (int ni = 0; ni < 4; ++ni)
#pragma unroll
            for (int kc = 0; kc < 2; ++kc)
                bf[ni][kc] = *(const bfrag*)&sm.s.B[cur][wn + ni * 16 + l15][((kc * 4 + quad) ^ (l15 & 7)) * 8];
#pragma unroll
        for (int kc = 0; kc < 2; ++kc)
#pragma unroll
            for (int mi = 0; mi < 4; ++mi)
#pragma unroll
                for (int ni = 0; ni < 4; ++ni)
                    acc[mi][ni] = __builtin_amdgcn_mfma_f32_16x16x32_bf16(af[mi][kc], bf[ni][kc], acc[mi][ni], 0, 0, 0);

        __syncthreads();                    // drains vmcnt (t+1 staged) + fences buf[cur]
    }

    // epilogue: 4 rounds; round t stages every wave's mi=t subtile (32x128)
#pragma unroll
    for (int t = 0; t < 4; ++t) {
        __syncthreads();
#pragma unroll
        for (int ni = 0; ni < 4; ++ni)
#pragma unroll
            for (int r = 0; r < 4; ++r) {
                int lr = (w >> 1) * 16 + quad * 4 + r;
                int lc = wn + ni * 16 + l15;
                if (outF) sm.ctf[lr][lc] = acc[t][ni][r];
                else      sm.ct [lr][lc] = f2b(acc[t][ni][r]);
            }
        __syncthreads();
        if (outF) {
#pragma unroll
            for (int i = 0; i < 4; ++i) {
                int cc = tid + i * 256;
                int lr = cc >> 5, c4 = (cc & 31) * 4;
                int grow = m0 + (lr >> 4) * 64 + t * 16 + (lr & 15);
                *(float4*)((float*)Cmat + (size_t)grow * N + n0 + c4) =
                    *(const float4*)&sm.ctf[lr][c4];
            }
        } else {
#pragma unroll
            for (int i = 0; i < 2; ++i) {
                int cc = tid + i * 256;
                int lr = cc >> 4, c8 = (cc & 15) * 8;
                int grow = m0 + (lr >> 4) * 64 + t * 16 + (lr & 15);
                *(uint4*)((unsigned short*)Cmat + (size_t)grow * N + n0 + c8) =
                    *(const uint4*)&sm.ct[lr][c8];
            }
        }
    }
}

// ---------------------------------------------------------------------------
// RoPE trig table: tab[t*64 + i1] = (cos, sin) of (pos+t) * 10000^(-2*i1/128).
// Same libm calls as the original in-rope path -> bit-identical trig values.
// ---------------------------------------------------------------------------
__global__ __launch_bounds__(256) void k_trig(float2* __restrict__ tab,
                                              const int* __restrict__ posPtr) {
    int tid = blockIdx.x * 256 + threadIdx.x;   // 131072 total
    int i1 = tid & 63, t = tid >> 6;
    float p = (float)(*posPtr + t);
    float f = exp2f(-(float)i1 * 0.20762050595278f);
    float th = p * f;
    tab[tid] = make_float2(cosf(th), sinf(th));
}

// ---------------------------------------------------------------------------
// RoPE in-place on bf16 X, table-driven, 2-wide (d and d+1 share the angle).
// ---------------------------------------------------------------------------
__global__ __launch_bounds__(256) void k_rope(unsigned short* __restrict__ X,
                                              const float2* __restrict__ tab,
                                              int lognh, int stride) {
    int tid = blockIdx.x * 256 + threadIdx.x;
    int d2 = tid & 31;
    int nh = 1 << lognh;
    int h = (tid >> 5) & (nh - 1);
    int row = tid >> (5 + lognh);
    int t = row & (TT - 1);
    size_t base = (size_t)row * stride + h * 128 + d2 * 2;
    unsigned int ua = *(const unsigned int*)(X + base);        // x1: d, d+1
    unsigned int ub = *(const unsigned int*)(X + base + 64);   // x2: d+64, d+65
    float x1a = b2f((unsigned short)(ua & 0xffff));
    float x1b = b2f((unsigned short)(ua >> 16));
    float x2a = b2f((unsigned short)(ub & 0xffff));
    float x2b = b2f((unsigned short)(ub >> 16));
    float2 cs1 = tab[t * 64 + d2];
    float2 cs2 = tab[t * 64 + d2 + 32];
    unsigned int o1 = (unsigned int)f2b(x1a * cs1.x - x2a * cs1.y)
                    | ((unsigned int)f2b(x1b * cs1.x - x2b * cs1.y) << 16);
    unsigned int o2 = (unsigned int)f2b(x2a * cs2.x + x1a * cs2.y)
                    | ((unsigned int)f2b(x2b * cs2.x + x1b * cs2.y) << 16);
    *(unsigned int*)(X + base)      = o1;
    *(unsigned int*)(X + base + 64) = o2;
}

// ---------------------------------------------------------------------------
// Flash attention, causal, GQA (16 q / 4 kv heads). Round-7 measured-good
// config: 512 threads, QBLK=128, paired q-tiles (i, 15-i); double-buffered
// K/V LDS, one barrier per K-step, register prefetch post-barrier;
// inactive-tile skip; interior fast path; T13 defer-max THR=8; swapped QK^T
// in-lane softmax. No setprio (m190: negative on barrier-synced structures;
// round-9's split-launch A/B was confounded by occupancy halving).
// ---------------------------------------------------------------------------
__device__ __forceinline__ void flash_pass(
    int qbase, int b, int h, int kvh,
    const unsigned short* __restrict__ QKV,
    const unsigned short* __restrict__ VbT,
    unsigned short* __restrict__ att,
    unsigned short (&Ks)[2][32][136],
    unsigned short (&Vt)[2][128][40],
    unsigned short (&Pt)[8][16][40]) {

    int tid = threadIdx.x;
    int w = tid >> 6, lane = tid & 63, quad = lane >> 4, l15 = lane & 15;

    bfrag qf[4];
    {
        size_t qrow = (size_t)(b * TT + qbase + w * 16 + l15);
        for (int kc = 0; kc < 4; ++kc)
            qf[kc] = *(const bfrag*)(QKV + qrow * 3072 + h * 128 + kc * 32 + quad * 8);
    }

    float mreg = NEG_BIG, lreg = 0.f;      // state for q = qgmin + l15
    facc o[8];
#pragma unroll
    for (int nb2 = 0; nb2 < 8; ++nb2)
#pragma unroll
        for (int r = 0; r < 4; ++r) o[nb2][r] = 0.f;

    int krow = tid >> 4, d8 = (tid & 15) * 8;
    int vd = tid >> 2, tc = (tid & 3) * 8;
    const unsigned short* Kg = QKV + (size_t)(b * TT) * 3072 + 2048 + kvh * 128;
    const unsigned short* Vg = VbT + (size_t)(kvh * 128 + vd) * 8192 + b * TT;

    const float sc = 0.08838834764831845f;   // 1/sqrt(128)
    int kmax = qbase + 128;
    int nt = kmax >> 5;
    int qgmin = qbase + w * 16;
    int myq = qgmin + l15;                   // this lane's q-row

    uint4 rk = *(const uint4*)(Kg + (size_t)krow * 3072 + d8);
    uint4 rv = *(const uint4*)(Vg + tc);

    for (int t = 0; t < nt; ++t) {
        int cur = t & 1;
        int k0 = t * 32;
        *(uint4*)&Ks[cur][krow][d8] = rk;
        *(uint4*)&Vt[cur][vd][tc]   = rv;
        __syncthreads();

        if (t + 1 < nt) {
            int k0n = k0 + 32;
            rk = *(const uint4*)(Kg + (size_t)(k0n + krow) * 3072 + d8);
            rv = *(const uint4*)(Vg + k0n + tc);
        }

        if (k0 > qgmin + 15) continue;       // fully-masked tile for this wave

        // swapped QK^T: A = K-frag, B = Q-frag -> D[k][q], q = l15
        facc s[2];
#pragma unroll
        for (int nb = 0; nb < 2; ++nb) {
#pragma unroll
            for (int r = 0; r < 4; ++r) s[nb][r] = 0.f;
#pragma unroll
            for (int kc = 0; kc < 4; ++kc) {
                bfrag kf = *(const bfrag*)&Ks[cur][nb * 16 + l15][kc * 32 + quad * 8];
                s[nb] = __builtin_amdgcn_mfma_f32_16x16x32_bf16(kf, qf[kc], s[nb], 0, 0, 0);
            }
        }

        bool fullT = (k0 + 31) <= qgmin;
        float v[2][4];
        if (fullT) {
#pragma unroll
            for (int nb = 0; nb < 2; ++nb)
#pragma unroll
                for (int r = 0; r < 4; ++r) v[nb][r] = s[nb][r] * sc;
        } else {
#pragma unroll
            for (int nb = 0; nb < 2; ++nb)
#pragma unroll
                for (int r = 0; r < 4; ++r) {
                    int kg = k0 + nb * 16 + quad * 4 + r;
                    v[nb][r] = (kg > myq) ? NEG_BIG : s[nb][r] * sc;
                }
        }

        // row max: 7 local fmax + 2-step fold
        float mx = fmaxf(fmaxf(fmaxf(v[0][0], v[0][1]), fmaxf(v[0][2], v[0][3])),
                         fmaxf(fmaxf(v[1][0], v[1][1]), fmaxf(v[1][2], v[1][3])));
        mx = fmaxf(mx, __shfl_xor(mx, 16, 64));
        mx = fmaxf(mx, __shfl_xor(mx, 32, 64));

        bool need = (mx > mreg + 8.f);       // T13 defer-max, THR=8
        float mnew = need ? mx : mreg;
        float alpha = need ? __expf(mreg - mnew) : 1.f;

        float p[2][4];
        float psum = 0.f;
#pragma unroll
        for (int nb = 0; nb < 2; ++nb)
#pragma unroll
            for (int r = 0; r < 4; ++r) {
                p[nb][r] = __expf(v[nb][r] - mnew);   // exp(-huge)=0 for masked
                psum += p[nb][r];
            }
        psum += __shfl_xor(psum, 16, 64);
        psum += __shfl_xor(psum, 32, 64);
        lreg = lreg * alpha + psum;
        mreg = mnew;

        // P -> LDS: lane writes 4 contiguous k per nb (8B each)
#pragma unroll
        for (int nb = 0; nb < 2; ++nb) {
            unsigned short pk[4];
#pragma unroll
            for (int r = 0; r < 4; ++r) pk[r] = f2b(p[nb][r]);
            *(uint2*)&Pt[w][l15][nb * 16 + quad * 4] = *(const uint2*)pk;
        }

        if (__any(need)) {                   // fetch per-q alpha, rescale o
#pragma unroll
            for (int r = 0; r < 4; ++r) {
                float al = __shfl(alpha, quad * 4 + r, 16);
#pragma unroll
                for (int nb2 = 0; nb2 < 8; ++nb2) o[nb2][r] *= al;
            }
        }

        asm volatile("s_waitcnt lgkmcnt(0)" ::: "memory");   // wave-local RAW on Pt[w]
        bfrag pf = *(const bfrag*)&Pt[w][l15][quad * 8];
#pragma unroll
        for (int nb2 = 0; nb2 < 8; ++nb2) {
            bfrag vf = *(const bfrag*)&Vt[cur][nb2 * 16 + l15][quad * 8];
            o[nb2] = __builtin_amdgcn_mfma_f32_16x16x32_bf16(pf, vf, o[nb2], 0, 0, 0);
        }
    }

    // final: fetch per-q l via width-16 shfl, divide, store
    float lr[4];
#pragma unroll
    for (int r = 0; r < 4; ++r) lr[r] = __shfl(lreg, quad * 4 + r, 16);
#pragma unroll
    for (int nb2 = 0; nb2 < 8; ++nb2)
#pragma unroll
        for (int r = 0; r < 4; ++r) {
            int qg = qbase + w * 16 + quad * 4 + r;
            att[(size_t)(b * TT + qg) * 2048 + h * 128 + nb2 * 16 + l15] =
                f2b(o[nb2][r] / lr[r]);
        }
}

__global__ __launch_bounds__(512, 4) void k_flash(const unsigned short* __restrict__ QKV,
                                                  const unsigned short* __restrict__ VbT,
                                                  unsigned short* __restrict__ att) {
    __shared__ alignas(16) unsigned short Ks[2][32][136];
    __shared__ alignas(16) unsigned short Vt[2][128][40];
    __shared__ alignas(16) unsigned short Pt[8][16][40];
    int bh = blockIdx.y;
    int b = bh >> 4, h = bh & 15;
    int kvh = h >> 2;
    int i = blockIdx.x;

    flash_pass(i * 128, b, h, kvh, QKV, VbT, att, Ks, Vt, Pt);
    __syncthreads();
    flash_pass((15 - i) * 128, b, h, kvh, QKV, VbT, att, Ks, Vt, Pt);
}

// ---------------------------------------------------------------------------
extern "C" void kernel_launch(void* const* d_in, const int* in_sizes, int n_in,
                              void* d_out, int out_size, void* d_ws, size_t ws_size,
                              hipStream_t stream) {
    const float* x  = (const float*)d_in[0];
    const float* Wq = (const float*)d_in[1];
    const float* Wk = (const float*)d_in[2];
    const float* Wv = (const float*)d_in[3];
    const float* Wo = (const float*)d_in[4];
    const int* pos  = (const int*)d_in[5];

    char* ws = (char*)d_ws;
    unsigned short* xb   = (unsigned short*)(ws + 0);          // 32 MB (8192x2048); reused as att out
    unsigned short* QKV  = (unsigned short*)(ws + 33554432);   // 48 MB (8192x3072)
    unsigned short* VbT  = (unsigned short*)(ws + 83886080);   //  8 MB (512x8192)
    unsigned short* WqT  = (unsigned short*)(ws + 92274688);   //  8 MB (2048x2048)
    unsigned short* WkvT = (unsigned short*)(ws + 100663296);  //  4 MB (1024x2048) -- contiguous with WqT
    unsigned short* WoT  = (unsigned short*)(ws + 104857600);  //  8 MB
    float2*         tab  = (float2*)(ws + 113246208);          //  1 MB rope trig table -> 114.25 MB

    // trig table (independent of everything; launch first)
    k_trig<<<512, 256, 0, stream>>>(tab, pos);

    // bf16 conversion + weight transposes (WqT|WkvT form one contiguous 3072x2048 Bt)
    k_cvt<<<8192, 256, 0, stream>>>(x, xb, 2097152);
    k_wt<<<dim3(32, 32), 256, 0, stream>>>(Wq, WqT, 2048);
    k_wt<<<dim3(8, 32),  256, 0, stream>>>(Wk, WkvT, 512);
    k_wt<<<dim3(8, 32),  256, 0, stream>>>(Wv, WkvT + (size_t)512 * 2048, 512);
    k_wt<<<dim3(32, 32), 256, 0, stream>>>(Wo, WoT, 2048);

    // fused Q|K|V projection: 2-phase, locked config
    k_gemm2ph<<<dim3(24, 64), 256, 0, stream>>>(xb, WqT, QKV, 8192, 3072, 2048, 0);

    // RoPE, table-driven (Q: 16 heads, cols 0..2047; K: 4 heads, cols 2048..2559)
    k_rope<<<16384, 256, 0, stream>>>(QKV, tab, 4, 3072);
    k_rope<<<4096,  256, 0, stream>>>(QKV + 2048, tab, 2, 3072);

    // V transpose for flash B-frag staging
    k_vt<<<dim3(8, 128), 256, 0, stream>>>(QKV, VbT);

    // causal GQA flash attention (swapped-QK softmax) -> xb, single launch
    k_flash<<<dim3(8, 64), 512, 0, stream>>>(QKV, VbT, xb);

    // output projection -> fp32 d_out: 2-phase, locked config
    k_gemm2ph<<<dim3(16, 64), 256, 0, stream>>>(xb, WoT, d_out, 8192, 2048, 2048, 1);
}